// Round 1
// baseline (174.372 us; speedup 1.0000x reference)
//
#include <hip/hip_runtime.h>

// Problem constants (structure is deterministic from the reference's
// _build_structure(): no randomness, so indices are compile-time known).
#define L_TOT 10752
#define NF    256
#define BATCHN 4096
#define KDIM  128

typedef __attribute__((ext_vector_type(8))) short short8;   // 8 bf16
typedef __attribute__((ext_vector_type(4))) float f32x4;

__device__ __forceinline__ unsigned short f2bf(float f) {
  unsigned int u = __float_as_uint(f);
  unsigned int r = (u + 0x7FFFu + ((u >> 16) & 1u)) >> 16;  // RNE
  return (unsigned short)r;
}

__device__ __forceinline__ float tanh_fast(float x) {
  // tanh(x) = 1 - 2/(1+e^{2x}); clamp avoids inf/inf. v_exp + v_rcp, ~1ulp each.
  float xc = fminf(fmaxf(x, -15.0f), 15.0f);
  float e2 = __builtin_amdgcn_exp2f(xc * 2.8853900817779268f); // 2*log2(e)
  float r  = __builtin_amdgcn_rcpf(e2 + 1.0f);
  return fmaf(-2.0f, r, 1.0f);
}

// ---------------- prep: x fp32 -> bf16 ----------------
__global__ __launch_bounds__(256) void prep_x(const float4* __restrict__ x4,
                                              ushort4* __restrict__ xb4, int n4) {
  int i = blockIdx.x * 256 + threadIdx.x;
  if (i < n4) {
    float4 v = x4[i];
    ushort4 o;
    o.x = f2bf(v.x); o.y = f2bf(v.y); o.z = f2bf(v.z); o.w = f2bf(v.w);
    xb4[i] = o;
  }
}

// ---------------- main: GEMM + tanh + conj/formula reductions ----------------
// Block: 4 waves; wave w owns 16 batch rows per iter, 4 iters -> 64x4=256 batches.
// One formula per block. NC = conjs, NT = padded lit tiles (NT*16 >= 4*NC).
template<int NC, int NT>
__device__ __forceinline__ void dnnf_body(
    const unsigned short* __restrict__ xb,   // [4096][128] bf16
    const float* __restrict__ weight,        // [128][10752]
    const float* __restrict__ bias,          // [10752]
    const float* __restrict__ lm,            // [128][256]
    float* __restrict__ dnnf,                // [256][4096]
    int f, int ls, int batch0,
    unsigned short* s_w,                     // [64*136]
    float* s_buf)                            // [4][64*16]
{
  constexpr int LF  = 4 * NC;
  constexpr int NC3 = NC / 3;
  const int tid  = threadIdx.x;
  const int lane = tid & 63;
  const int wv   = tid >> 6;
  const int n    = lane & 15;
  const int q    = lane >> 4;

  // --- stage masked weights for this formula into LDS as bf16 [lit][k] ---
  const int total = KDIM * LF;
  for (int e = tid; e < total; e += 256) {
    int k = e / LF;                  // LF constexpr -> magic mul
    int j = e - k * LF;
    float m = (fabsf(lm[k * NF + f]) > 1.0f) ? 1.0f : 0.0f;
    float v = weight[k * L_TOT + ls + j] * m;
    s_w[j * 136 + k] = f2bf(v);
  }
  __syncthreads();

  // --- hoist B fragments into registers (reused over all 4 batch iters) ---
  short8 fb[NT][4];
#pragma unroll
  for (int t = 0; t < NT; ++t)
#pragma unroll
    for (int kk = 0; kk < 4; ++kk)
      fb[t][kk] = *reinterpret_cast<const short8*>(&s_w[(t * 16 + n) * 136 + kk * 32 + q * 8]);

  float bfrag[NT];
#pragma unroll
  for (int t = 0; t < NT; ++t) {
    int j = t * 16 + n;
    bfrag[t] = (j < LF) ? bias[ls + j] : 0.0f;
  }

  float* buf = s_buf + wv * (64 * 16);   // per-wave [lit][16 batch] fp32

  for (int iter = 0; iter < 4; ++iter) {
    int brow = batch0 + iter * 64 + wv * 16;
    const unsigned short* xrow = xb + (size_t)(brow + n) * KDIM;
    short8 fa[4];
#pragma unroll
    for (int kk = 0; kk < 4; ++kk)
      fa[kk] = *reinterpret_cast<const short8*>(xrow + kk * 32 + q * 8);

    f32x4 acc[NT];
#pragma unroll
    for (int t = 0; t < NT; ++t) acc[t] = (f32x4){0.f, 0.f, 0.f, 0.f};
#pragma unroll
    for (int kk = 0; kk < 4; ++kk)
#pragma unroll
      for (int t = 0; t < NT; ++t)
        acc[t] = __builtin_amdgcn_mfma_f32_16x16x32_bf16(fa[kk], fb[t][kk], acc[t], 0, 0, 0);

    // epilogue: literal tanh -> per-wave LDS buffer [lit][16]
    // C layout (m89): col(lit)=lane&15, row(batch)=q*4+reg.
#pragma unroll
    for (int t = 0; t < NT; ++t) {
      f32x4 tv;
#pragma unroll
      for (int r = 0; r < 4; ++r)
        tv[r] = tanh_fast(acc[t][r] + bfrag[t]);
      *reinterpret_cast<f32x4*>(&buf[(t * 16 + n) * 16 + q * 4]) = tv;
    }

    // conj reduction: lane (b=n, quad q) handles conjs c = q, q+4, ...
    float fs = 0.0f;
    for (int c = q; c < NC; c += 4) {
      int d, off;
      if (c < NC3)          { d = 2; off = 2 * c; }
      else if (c < 2 * NC3) { d = 4; off = 2 * NC3 + 4 * (c - NC3); }
      else                  { d = 6; off = 6 * NC3 + 6 * (c - 2 * NC3); }
      float s = 0.0f;
      for (int dd = 0; dd < d; ++dd) s += buf[(off + dd) * 16 + n];
      fs += tanh_fast(s - (float)d + 1.5f);   // tanh(conj_sum - and_bias + 1.5)
    }
    // combine the 4 quads (same batch col n)
    fs += __shfl_xor(fs, 16);
    fs += __shfl_xor(fs, 32);
    float dv = tanh_fast(fs + (float)NC - 1.5f);  // tanh(form_sum + or_bias - 1.5)
    if (lane < 16)
      dnnf[(size_t)f * BATCHN + brow + lane] = dv;
  }
}

__global__ __launch_bounds__(256) void dnnf_main(
    const unsigned short* __restrict__ xb,
    const float* __restrict__ weight,
    const float* __restrict__ bias,
    const float* __restrict__ lm,
    float* __restrict__ dnnf)
{
  __shared__ unsigned short s_w[64 * 136];
  __shared__ float s_buf[4 * 64 * 16];
  int bi = blockIdx.x;
  int f = bi >> 4;
  int batch0 = (bi & 15) * 256;
  int g = f >> 6;
  int fo = f & 63;
  if (g == 0)      dnnf_body<6, 2>(xb, weight, bias, lm, dnnf, f, 0    + fo * 24, batch0, s_w, s_buf);
  else if (g == 1) dnnf_body<9, 3>(xb, weight, bias, lm, dnnf, f, 1536 + fo * 36, batch0, s_w, s_buf);
  else if (g == 2) dnnf_body<12, 3>(xb, weight, bias, lm, dnnf, f, 3840 + fo * 48, batch0, s_w, s_buf);
  else             dnnf_body<15, 4>(xb, weight, bias, lm, dnnf, f, 6912 + fo * 60, batch0, s_w, s_buf);
}

// ---------------- loc + softmax + multiply ----------------
// Block: 16 batches x 256 formulas, 256 threads: thread (b=tid&15, fq=tid>>4)
// computes 16 formulas' distances over K=128 in fp32.
__global__ __launch_bounds__(256) void loc_softmax(
    const float* __restrict__ x,       // [4096][128]
    const float* __restrict__ mu,      // [256][128]
    const float* __restrict__ sigma,   // [256][128]
    const float* __restrict__ temp,    // [1]
    const float* __restrict__ dnnf,    // [256][4096]
    float* __restrict__ out)           // [4096][256]
{
  __shared__ float s_x[16 * 132];
  __shared__ float s_ps[16 * 16];
  __shared__ float s_tot[16];
  int tid = threadIdx.x;
  int b0 = blockIdx.x * 16;
  for (int e = tid; e < 16 * 128; e += 256) {
    int b = e >> 7, k = e & 127;
    s_x[b * 132 + k] = x[(size_t)(b0 + b) * 128 + k];
  }
  __syncthreads();

  int b = tid & 15;
  int fq = tid >> 4;
  float acc[16];
#pragma unroll
  for (int j = 0; j < 16; ++j) acc[j] = 0.0f;

  for (int kc = 0; kc < 8; ++kc) {
    float xr[16];
#pragma unroll
    for (int i = 0; i < 16; ++i) xr[i] = s_x[b * 132 + kc * 16 + i];
#pragma unroll
    for (int j = 0; j < 16; ++j) {
      int f = fq * 16 + j;
      const float4* mup = reinterpret_cast<const float4*>(mu + f * 128 + kc * 16);
      const float4* sgp = reinterpret_cast<const float4*>(sigma + f * 128 + kc * 16);
      float a = acc[j];
#pragma unroll
      for (int v = 0; v < 4; ++v) {
        float4 m4 = mup[v];
        float4 s4 = sgp[v];
        float d0 = (xr[v * 4 + 0] - m4.x) * s4.x;
        float d1 = (xr[v * 4 + 1] - m4.y) * s4.y;
        float d2 = (xr[v * 4 + 2] - m4.z) * s4.z;
        float d3 = (xr[v * 4 + 3] - m4.w) * s4.w;
        a = fmaf(d0, d0, a); a = fmaf(d1, d1, a);
        a = fmaf(d2, d2, a); a = fmaf(d3, d3, a);
      }
      acc[j] = a;
    }
  }

  float T = temp[0];
  float sig = 1.0f / (1.0f + __expf(-T));
  float e16[16];
  float ps = 0.0f;
#pragma unroll
  for (int j = 0; j < 16; ++j) {
    float loc = __expf(-sqrtf(acc[j]));
    float ez = __expf(sig * loc);
    e16[j] = ez;
    ps += ez;
  }
  s_ps[b * 16 + fq] = ps;
  __syncthreads();
  if (tid < 16) {
    float tot = 0.0f;
#pragma unroll
    for (int i = 0; i < 16; ++i) tot += s_ps[tid * 16 + i];
    s_tot[tid] = tot;
  }
  __syncthreads();
  float rs = 1.0f / s_tot[b];
  int bg = b0 + b;
#pragma unroll
  for (int j4 = 0; j4 < 4; ++j4) {
    float4 o;
    float* po = reinterpret_cast<float*>(&o);
#pragma unroll
    for (int u = 0; u < 4; ++u) {
      int j = j4 * 4 + u;
      int f = fq * 16 + j;
      po[u] = dnnf[(size_t)f * BATCHN + bg] * e16[j] * rs;
    }
    *reinterpret_cast<float4*>(out + (size_t)bg * 256 + fq * 16 + j4 * 4) = o;
  }
}

extern "C" void kernel_launch(void* const* d_in, const int* in_sizes, int n_in,
                              void* d_out, int out_size, void* d_ws, size_t ws_size,
                              hipStream_t stream) {
  const float* x      = (const float*)d_in[0];
  const float* weight = (const float*)d_in[1];
  const float* bias   = (const float*)d_in[2];
  const float* lm     = (const float*)d_in[3];
  const float* mu     = (const float*)d_in[4];
  const float* sigma  = (const float*)d_in[5];
  const float* temp   = (const float*)d_in[6];
  // d_in[7..9]: structure index arrays — deterministic, baked in at compile time.
  float* out = (float*)d_out;

  unsigned short* xb = (unsigned short*)d_ws;                       // 1 MB bf16 x
  float* dnnf = (float*)((char*)d_ws + (size_t)BATCHN * KDIM * 2);  // 4 MB [f][b]

  prep_x<<<512, 256, 0, stream>>>((const float4*)x, (ushort4*)xb, BATCHN * KDIM / 4);
  dnnf_main<<<4096, 256, 0, stream>>>(xb, weight, bias, lm, dnnf);
  loc_softmax<<<BATCHN / 16, 256, 0, stream>>>(x, mu, sigma, temp, dnnf, out);
}